// Round 3
// baseline (723.064 us; speedup 1.0000x reference)
//
#include <hip/hip_runtime.h>
#include <math.h>

typedef float  f32x4  __attribute__((ext_vector_type(4)));
typedef short  bf16x8 __attribute__((ext_vector_type(8)));
typedef unsigned short ushort8 __attribute__((ext_vector_type(8)));

#define NTOK 8192
#define H    1024
#define FF   4096
#define NEXP 8
#define MAXTILES 40   // sum ceil(c_e/256) <= 8192/256 + 8

// fp32 -> bf16 RNE
__device__ __forceinline__ unsigned short f2bf(float f) {
    unsigned int u = __float_as_uint(f);
    u += 0x7fffu + ((u >> 16) & 1u);
    return (unsigned short)(u >> 16);
}

// async global->LDS, 16B/lane; LDS dest is wave-uniform base + lane*16
__device__ __forceinline__ void gload16(const void* g, void* l) {
    __builtin_amdgcn_global_load_lds((const __attribute__((address_space(1))) void*)g,
                                     (__attribute__((address_space(3))) void*)l, 16, 0, 0);
}

// ---------------- router: 1 wave per token ----------------
__global__ void __launch_bounds__(256)
router_k(const float* __restrict__ x, const float* __restrict__ rw, const float* __restrict__ rb,
         float* __restrict__ maxp, int* __restrict__ maxi, int* __restrict__ counts) {
    const int lane = threadIdx.x & 63;
    const int t = blockIdx.x * 4 + (threadIdx.x >> 6);
    const float4* xr = (const float4*)(x + (size_t)t * H);
    float acc[NEXP];
#pragma unroll
    for (int e = 0; e < NEXP; ++e) acc[e] = 0.f;
#pragma unroll
    for (int c = 0; c < 4; ++c) {
        float4 xv = xr[lane + 64 * c];
#pragma unroll
        for (int e = 0; e < NEXP; ++e) {
            float4 wv = ((const float4*)(rw + e * H))[lane + 64 * c];
            acc[e] += xv.x * wv.x + xv.y * wv.y + xv.z * wv.z + xv.w * wv.w;
        }
    }
#pragma unroll
    for (int e = 0; e < NEXP; ++e) {
#pragma unroll
        for (int off = 32; off > 0; off >>= 1) acc[e] += __shfl_xor(acc[e], off);
    }
    if (lane == 0) {
        float best = -1e30f; int bi = 0;
#pragma unroll
        for (int e = 0; e < NEXP; ++e) {
            float v = acc[e] + rb[e];
            acc[e] = v;
            if (v > best) { best = v; bi = e; }
        }
        float s = 0.f;
#pragma unroll
        for (int e = 0; e < NEXP; ++e) s += __expf(acc[e] - best);
        maxp[t] = 1.0f / s;
        maxi[t] = bi;
        atomicAdd(&counts[bi * 32], 1);   // 128B-padded counters
    }
}

// ---------------- scan: 128-aligned buckets, 256-row tile table ----------------
__global__ void scan_k(const int* __restrict__ counts, int* __restrict__ offs,
                       int* __restrict__ tile_e, int* __restrict__ tile_r0, int* __restrict__ ntiles) {
    int off = 0, ti = 0;
    for (int e = 0; e < NEXP; ++e) {
        offs[e] = off;
        int c = counts[e * 32];
        int nt = (c + 255) >> 8;
        for (int j = 0; j < nt; ++j) { tile_e[ti] = e; tile_r0[ti] = off + (j << 8); ++ti; }
        off += ((c + 127) >> 7) << 7;
    }
    offs[NEXP] = off;
    *ntiles = ti;
}

// ---------------- gather tokens into bucketed bf16 A ----------------
__global__ void __launch_bounds__(256)
gather_k(const float* __restrict__ x, const int* __restrict__ maxi, const int* __restrict__ offs,
         int* __restrict__ cursor, int* __restrict__ perm, unsigned short* __restrict__ ab) {
    const int lane = threadIdx.x & 63;
    const int t = blockIdx.x * 4 + (threadIdx.x >> 6);
    int pos = 0;
    if (lane == 0) {
        int e = maxi[t];
        pos = offs[e] + atomicAdd(&cursor[e * 32], 1);
        perm[pos] = t;
    }
    pos = __shfl(pos, 0);
    const float4* xr = (const float4*)(x + (size_t)t * H);
    ushort4* ar = (ushort4*)(ab + (size_t)pos * H);
#pragma unroll
    for (int c = 0; c < 4; ++c) {
        float4 v = xr[lane + 64 * c];
        ar[lane + 64 * c] = make_ushort4(f2bf(v.x), f2bf(v.y), f2bf(v.z), f2bf(v.w));
    }
}

// ---------------- fp32 -> bf16 convert, w1+w2 in one pass ----------------
__global__ void __launch_bounds__(256)
cvt_k(const float4* __restrict__ w1, const float4* __restrict__ w2,
      ushort4* __restrict__ d1, ushort4* __restrict__ d2, int n4) {
    const int stride = gridDim.x * blockDim.x;
    for (int i = blockIdx.x * blockDim.x + threadIdx.x; i < n4; i += stride) {
        float4 v = w1[i]; d1[i] = make_ushort4(f2bf(v.x), f2bf(v.y), f2bf(v.z), f2bf(v.w));
        float4 u = w2[i]; d2[i] = make_ushort4(f2bf(u.x), f2bf(u.y), f2bf(u.z), f2bf(u.w));
    }
}

// ================= 256x256 8-phase GEMM core =================
// Same derived schedule as round 2 (correctness-proven); acc pinned to AGPRs.
// KE = K extent per block (elements), LDE = row stride (elements).

#define READ_A(BA, MH)                                                          \
  _Pragma("unroll") for (int j = 0; j < 4; ++j)                                 \
    _Pragma("unroll") for (int kk = 0; kk < 2; ++kk)                            \
      a_[j][kk] = *(const bf16x8*)((BA) + (wr*8 + (MH)*4 + j)*2048 + kk*1024 + aoffb);

#define READ_B(BB, NH, BR)                                                      \
  _Pragma("unroll") for (int j2 = 0; j2 < 2; ++j2)                              \
    _Pragma("unroll") for (int kk = 0; kk < 2; ++kk)                            \
      BR[j2][kk] = *(const bf16x8*)((BB) + (wc*4 + (NH)*2 + j2)*2048 + kk*1024 + aoffb);

#define MFMA_Q(MH, NH, BR)                                                      \
  __builtin_amdgcn_s_setprio(1);                                                \
  _Pragma("unroll") for (int kk = 0; kk < 2; ++kk)                              \
    _Pragma("unroll") for (int j = 0; j < 4; ++j)                               \
      _Pragma("unroll") for (int j2 = 0; j2 < 2; ++j2)                          \
        asm volatile("v_mfma_f32_16x16x32_bf16 %0, %1, %2, %0"                  \
          : "+a"(acc[(MH)*4 + j][(NH)*2 + j2]) : "v"(a_[j][kk]), "v"(BR[j2][kk])); \
  __builtin_amdgcn_s_setprio(0);

#define BAR() __builtin_amdgcn_s_barrier()

template<int KE, int LDE>
__device__ __forceinline__ void gemm8_core(const char* __restrict__ Ag, const char* __restrict__ Bg,
                                           char* lds, f32x4 (&acc)[8][4]) {
    constexpr int LD2 = LDE * 2;          // row stride bytes
    const int tid = threadIdx.x, l = tid & 63, w = tid >> 6;
    const int wr = w >> 2, wc = w & 3;
    const int term  = ((l >> 4) * 8) ^ (((l >> 3) & 1) << 4);
    const int aoffb = (l & 15) * 64 + term * 2;

    char* const A0 = lds;          char* const B0 = lds + 32768;
    char* const A1 = lds + 65536;  char* const B1 = lds + 98304;

    int offA[2][2], offB[2][2], dstA[2][2], dstB[2][2];
#pragma unroll
    for (int q = 0; q < 2; ++q) {
        const int s  = q * 8 + w;
        const int lr = l >> 2;
        const int h  = ((s >> 1) << 4) + lr;
        const int c  = ((s & 1) << 5) + (((l & 3) * 8) ^ ((l & 32) >> 1));
#pragma unroll
        for (int half = 0; half < 2; ++half) {
            const int rA = (h & 63) + ((h >> 6) << 7) + (half << 6);
            const int rB = (h & 31) + ((h >> 5) << 6) + (half << 5);
            offA[q][half] = rA * LD2 + c * 2;
            offB[q][half] = rB * LD2 + c * 2;
            dstA[q][half] = ((((s >> 1) & 3) + (half << 2) + ((s >> 3) << 3)) << 11) + ((s & 1) << 10);
            dstB[q][half] = ((((s >> 1) & 1) + (half << 1) + ((s >> 2) << 2)) << 11) + ((s & 1) << 10);
        }
    }
    auto SA = [&](char* dst, int half, int kt) {
        gload16(Ag + offA[0][half] + kt * 128, dst + dstA[0][half]);
        gload16(Ag + offA[1][half] + kt * 128, dst + dstA[1][half]);
    };
    auto SB = [&](char* dst, int half, int kt) {
        gload16(Bg + offB[0][half] + kt * 128, dst + dstB[0][half]);
        gload16(Bg + offB[1][half] + kt * 128, dst + dstB[1][half]);
    };

    SA(A0, 0, 0); SB(B0, 0, 0); SB(B0, 1, 0); SA(A0, 1, 0);
    SA(A1, 0, 1); SB(B1, 0, 1); SB(B1, 1, 1);
    asm volatile("s_waitcnt vmcnt(6)" ::: "memory");
    BAR();

    constexpr int NKT = KE / 64;
    bf16x8 a_[4][2], b0_[2][2], b1_[2][2];
#pragma unroll 1
    for (int k0 = 0; k0 < NKT; k0 += 2) {
        const int k1 = k0 + 1;
        READ_A(A0, 0) READ_B(B0, 0, b0_)
        SA(A1, 1, k1);
        BAR(); MFMA_Q(0, 0, b0_) BAR();
        READ_B(B0, 1, b1_)
        SA(A0, 0, k0 + 2);
        BAR(); MFMA_Q(0, 1, b1_) BAR();
        READ_A(A0, 1)
        SB(B0, 0, k0 + 2);
        BAR(); MFMA_Q(1, 1, b1_) BAR();
        SB(B0, 1, k0 + 2);
        asm volatile("s_waitcnt vmcnt(4)" ::: "memory");
        BAR(); MFMA_Q(1, 0, b0_) BAR();
        READ_A(A1, 0) READ_B(B1, 0, b0_)
        SA(A0, 1, k0 + 2);
        BAR(); MFMA_Q(0, 0, b0_) BAR();
        READ_B(B1, 1, b1_)
        SA(A1, 0, k1 + 2);
        BAR(); MFMA_Q(0, 1, b1_) BAR();
        READ_A(A1, 1)
        SB(B1, 0, k1 + 2);
        BAR(); MFMA_Q(1, 1, b1_) BAR();
        SB(B1, 1, k1 + 2);
        asm volatile("s_waitcnt vmcnt(4)" ::: "memory");
        BAR(); MFMA_Q(1, 0, b0_) BAR();
        // overrun stages (kt >= NKT) stay within allocated ws; never consumed.
    }
}

// ---------------- GEMM1: inter = gelu(A @ w1[e]^T + b1[e]) ----------------
// 1-D grid 640 = 16 panels x 40 tiles; T1 XCD swizzle, x-major order.
__global__ void __launch_bounds__(512, 2)
gemm1_k(const unsigned short* __restrict__ ab, const unsigned short* __restrict__ w1b,
        const float* __restrict__ b1, unsigned short* __restrict__ inter,
        const int* __restrict__ tile_e, const int* __restrict__ tile_r0,
        const int* __restrict__ ntiles, const int* __restrict__ offs) {
    const int bid = blockIdx.x;
    const int wkid = (bid & 7) * 80 + (bid >> 3);   // bijective, 640 % 8 == 0
    const int xb = wkid / MAXTILES, yb = wkid % MAXTILES;
    if (yb >= *ntiles) return;
    __shared__ char lds[131072];
    const int e = tile_e[yb], row0 = tile_r0[yb];
    const int f0 = xb * 256;
    f32x4 acc[8][4];
#pragma unroll
    for (int m = 0; m < 8; ++m)
#pragma unroll
        for (int n = 0; n < 4; ++n)
#pragma unroll
            for (int j = 0; j < 4; ++j) acc[m][n][j] = 0.f;

    gemm8_core<H, H>((const char*)(ab + (size_t)row0 * H),
                     (const char*)(w1b + ((size_t)e * FF + f0) * H), lds, acc);

    // drain in-flight overrun stages before reusing LDS, then repack C via LDS
    asm volatile("s_waitcnt vmcnt(0)" ::: "memory");
    __syncthreads();
    const int tid = threadIdx.x, l = tid & 63, w = tid >> 6, wr = w >> 2, wc = w & 3;
    const int q = (l >> 4) & 3, lc = l & 15;
    unsigned short* cl = (unsigned short*)lds;
    float bias[4];
#pragma unroll
    for (int n = 0; n < 4; ++n) bias[n] = b1[e * FF + f0 + wc * 64 + n * 16 + lc];
    const int rowb = wr * 128 + q * 4;              // lane's base C-row in tile
#pragma unroll
    for (int n = 0; n < 4; ++n) {
        const int coln = (wc * 64 + n * 16 + lc) ^ (q << 4);   // ((row>>2)&3)==q for all m,j
#pragma unroll
        for (int m = 0; m < 8; ++m)
#pragma unroll
            for (int j = 0; j < 4; ++j) {
                float v = acc[m][n][j] + bias[n];
                float ex = __expf(1.5957691216057308f * v * (1.0f + 0.044715f * v * v));
                float u  = v - v / (ex + 1.0f);
                cl[(rowb + m * 16 + j) * 256 + coln] = f2bf(u);
            }
    }
    __syncthreads();
    const int rend = offs[e + 1];
    const int rsub = tid >> 5, cblk = (tid & 31) * 8;
    const int rxor = ((rsub >> 2) & 3) << 4;        // ((r>>2)&3) is it-invariant
#pragma unroll
    for (int it = 0; it < 16; ++it) {
        const int r = it * 16 + rsub;
        if (row0 + r < rend) {
            ushort8 val = *(const ushort8*)&cl[r * 256 + (cblk ^ rxor)];
            *(ushort8*)&inter[(size_t)(row0 + r) * FF + f0 + cblk] = val;
        }
    }
}

// ---------------- GEMM2: out += (inter @ w2[e]^T)*p (2-way split-K, atomic) ----------------
// 1-D grid 320 = (4 panels x 2 splits) x 40 tiles; each XCD owns one (panel,split).
__global__ void __launch_bounds__(512, 2)
gemm2_k(const unsigned short* __restrict__ inter, const unsigned short* __restrict__ w2b,
        const float* __restrict__ b2, float* __restrict__ out, float* __restrict__ outb,
        const int* __restrict__ tile_e, const int* __restrict__ tile_r0, const int* __restrict__ ntiles,
        const int* __restrict__ counts, const int* __restrict__ offs,
        const int* __restrict__ perm, const float* __restrict__ maxp) {
    const int bid = blockIdx.x;
    const int wkid = (bid & 7) * 40 + (bid >> 3);   // bijective, 320 % 8 == 0
    const int combo = wkid / MAXTILES, yb = wkid % MAXTILES;
    const int xb = combo >> 1, sp = combo & 1;
    if (yb >= *ntiles) return;
    __shared__ char lds[131072];
    const int e = tile_e[yb], row0 = tile_r0[yb];
    const int h0 = xb * 256;
    f32x4 acc[8][4];
#pragma unroll
    for (int m = 0; m < 8; ++m)
#pragma unroll
        for (int n = 0; n < 4; ++n)
#pragma unroll
            for (int j = 0; j < 4; ++j) acc[m][n][j] = 0.f;

    gemm8_core<2048, FF>((const char*)(inter + (size_t)row0 * FF + sp * 2048),
                         (const char*)(w2b + ((size_t)e * H + h0) * FF + sp * 2048), lds, acc);

    const int l = threadIdx.x & 63, w = threadIdx.x >> 6, wr = w >> 2, wc = w & 3;
    const int cnt = counts[e * 32], offe = offs[e];
#pragma unroll
    for (int m = 0; m < 8; ++m) {
#pragma unroll
        for (int j = 0; j < 4; ++j) {
            const int grow = row0 + wr * 128 + m * 16 + ((l >> 4) << 2) + j;
            if (grow - offe < cnt) {
                const int t = perm[grow];
                const float p = maxp[t];
#pragma unroll
                for (int n = 0; n < 4; ++n) {
                    const int col = h0 + wc * 64 + n * 16 + (l & 15);
                    unsafeAtomicAdd(&out[(size_t)t * H + col], acc[m][n][j] * p);
                    if (sp == 0) outb[(size_t)t * H + col] = b2[e * H + col] * p;
                }
            }
        }
    }
}

// ---------------- host launch ----------------
extern "C" void kernel_launch(void* const* d_in, const int* in_sizes, int n_in,
                              void* d_out, int out_size, void* d_ws, size_t ws_size,
                              hipStream_t stream) {
    const float* x  = (const float*)d_in[0];
    const float* rw = (const float*)d_in[1];
    const float* rb = (const float*)d_in[2];
    const float* w1 = (const float*)d_in[3];
    const float* b1 = (const float*)d_in[4];
    const float* w2 = (const float*)d_in[5];
    const float* b2 = (const float*)d_in[6];
    float* out  = (float*)d_out;
    float* outb = out + (size_t)NTOK * H;

    char* ws = (char*)d_ws;
    unsigned short* W1B   = (unsigned short*)(ws);                 // 67108864
    unsigned short* W2B   = (unsigned short*)(ws + 67108864);      // 67108864
    unsigned short* AB    = (unsigned short*)(ws + 134217728);     // 18874368 (9216 x 1024)
    unsigned short* INTER = (unsigned short*)(ws + 153092096);     // 75497472 (9216 x 4096)
    float* MAXP    = (float*)(ws + 228589568);
    int*   MAXI    = (int*)  (ws + 228622336);
    int*   PERM    = (int*)  (ws + 228655104);
    int*   COUNTS  = (int*)  (ws + 228691968);
    int*   CURSOR  = (int*)  (ws + 228692992);
    int*   OFFS    = (int*)  (ws + 228694016);
    int*   TILE_E  = (int*)  (ws + 228694080);
    int*   TILE_R0 = (int*)  (ws + 228694336);
    int*   NTILES  = (int*)  (ws + 228694592);

    (void)hipMemsetAsync(COUNTS, 0, 2048, stream);           // counts + cursors
    (void)hipMemsetAsync(out, 0, (size_t)NTOK * H * 4, stream); // split-K accumulator base

    router_k<<<NTOK / 4, 256, 0, stream>>>(x, rw, rb, MAXP, MAXI, COUNTS);
    scan_k<<<1, 1, 0, stream>>>(COUNTS, OFFS, TILE_E, TILE_R0, NTILES);
    gather_k<<<NTOK / 4, 256, 0, stream>>>(x, MAXI, OFFS, CURSOR, PERM, AB);
    cvt_k<<<4096, 256, 0, stream>>>((const float4*)w1, (const float4*)w2,
                                    (ushort4*)W1B, (ushort4*)W2B, NEXP * FF * H / 4);
    gemm1_k<<<16 * MAXTILES, 512, 0, stream>>>(AB, W1B, b1, INTER,
                                               TILE_E, TILE_R0, NTILES, OFFS);
    gemm2_k<<<8 * MAXTILES, 512, 0, stream>>>(INTER, W2B, b2, out, outb,
                                              TILE_E, TILE_R0, NTILES,
                                              COUNTS, OFFS, PERM, MAXP);
}

// Round 4
// 493.455 us; speedup vs baseline: 1.4653x; 1.4653x over previous
//
#include <hip/hip_runtime.h>
#include <math.h>

typedef float  f32x4  __attribute__((ext_vector_type(4)));
typedef short  bf16x8 __attribute__((ext_vector_type(8)));
typedef unsigned short ushort8 __attribute__((ext_vector_type(8)));

#define NTOK 8192
#define H    1024
#define FF   4096
#define NEXP 8
#define MAXTILES 40   // 256-row tiles: sum ceil(c_e/256) <= 8192/256 + 8
#define MAXT128  72   // 128-row tiles: sum ceil(c_e/128) <= 8192/128 + 8

// fp32 -> bf16 RNE
__device__ __forceinline__ unsigned short f2bf(float f) {
    unsigned int u = __float_as_uint(f);
    u += 0x7fffu + ((u >> 16) & 1u);
    return (unsigned short)(u >> 16);
}

// async global->LDS, 16B/lane; LDS dest is wave-uniform base + lane*16
__device__ __forceinline__ void gload16(const void* g, void* l) {
    __builtin_amdgcn_global_load_lds((const __attribute__((address_space(1))) void*)g,
                                     (__attribute__((address_space(3))) void*)l, 16, 0, 0);
}

// ---------------- router: 1 wave per token ----------------
__global__ void __launch_bounds__(256)
router_k(const float* __restrict__ x, const float* __restrict__ rw, const float* __restrict__ rb,
         float* __restrict__ maxp, int* __restrict__ maxi, int* __restrict__ counts) {
    const int lane = threadIdx.x & 63;
    const int t = blockIdx.x * 4 + (threadIdx.x >> 6);
    const float4* xr = (const float4*)(x + (size_t)t * H);
    float acc[NEXP];
#pragma unroll
    for (int e = 0; e < NEXP; ++e) acc[e] = 0.f;
#pragma unroll
    for (int c = 0; c < 4; ++c) {
        float4 xv = xr[lane + 64 * c];
#pragma unroll
        for (int e = 0; e < NEXP; ++e) {
            float4 wv = ((const float4*)(rw + e * H))[lane + 64 * c];
            acc[e] += xv.x * wv.x + xv.y * wv.y + xv.z * wv.z + xv.w * wv.w;
        }
    }
#pragma unroll
    for (int e = 0; e < NEXP; ++e) {
#pragma unroll
        for (int off = 32; off > 0; off >>= 1) acc[e] += __shfl_xor(acc[e], off);
    }
    if (lane == 0) {
        float best = -1e30f; int bi = 0;
#pragma unroll
        for (int e = 0; e < NEXP; ++e) {
            float v = acc[e] + rb[e];
            acc[e] = v;
            if (v > best) { best = v; bi = e; }
        }
        float s = 0.f;
#pragma unroll
        for (int e = 0; e < NEXP; ++e) s += __expf(acc[e] - best);
        maxp[t] = 1.0f / s;
        maxi[t] = bi;
        atomicAdd(&counts[bi * 32], 1);   // 128B-padded counters
    }
}

// ---------------- scan: 128-aligned buckets; 256-row and 128-row tile tables ----------------
__global__ void scan_k(const int* __restrict__ counts, int* __restrict__ offs,
                       int* __restrict__ tile_e, int* __restrict__ tile_r0, int* __restrict__ ntiles,
                       int* __restrict__ t128_e, int* __restrict__ t128_r0, int* __restrict__ nt128) {
    int off = 0, ti = 0, ti2 = 0;
    for (int e = 0; e < NEXP; ++e) {
        offs[e] = off;
        int c = counts[e * 32];
        int nt = (c + 255) >> 8;
        for (int j = 0; j < nt; ++j) { tile_e[ti] = e; tile_r0[ti] = off + (j << 8); ++ti; }
        int n2 = (c + 127) >> 7;
        for (int j = 0; j < n2; ++j) { t128_e[ti2] = e; t128_r0[ti2] = off + (j << 7); ++ti2; }
        off += n2 << 7;
    }
    offs[NEXP] = off;
    *ntiles = ti;
    *nt128 = ti2;
}

// ---------------- gather tokens into bucketed bf16 A ----------------
__global__ void __launch_bounds__(256)
gather_k(const float* __restrict__ x, const int* __restrict__ maxi, const int* __restrict__ offs,
         int* __restrict__ cursor, int* __restrict__ perm, unsigned short* __restrict__ ab) {
    const int lane = threadIdx.x & 63;
    const int t = blockIdx.x * 4 + (threadIdx.x >> 6);
    int pos = 0;
    if (lane == 0) {
        int e = maxi[t];
        pos = offs[e] + atomicAdd(&cursor[e * 32], 1);
        perm[pos] = t;
    }
    pos = __shfl(pos, 0);
    const float4* xr = (const float4*)(x + (size_t)t * H);
    ushort4* ar = (ushort4*)(ab + (size_t)pos * H);
#pragma unroll
    for (int c = 0; c < 4; ++c) {
        float4 v = xr[lane + 64 * c];
        ar[lane + 64 * c] = make_ushort4(f2bf(v.x), f2bf(v.y), f2bf(v.z), f2bf(v.w));
    }
}

// ---------------- fp32 -> bf16 convert, w1+w2 in one pass ----------------
__global__ void __launch_bounds__(256)
cvt_k(const float4* __restrict__ w1, const float4* __restrict__ w2,
      ushort4* __restrict__ d1, ushort4* __restrict__ d2, int n4) {
    const int stride = gridDim.x * blockDim.x;
    for (int i = blockIdx.x * blockDim.x + threadIdx.x; i < n4; i += stride) {
        float4 v = w1[i]; d1[i] = make_ushort4(f2bf(v.x), f2bf(v.y), f2bf(v.z), f2bf(v.w));
        float4 u = w2[i]; d2[i] = make_ushort4(f2bf(u.x), f2bf(u.y), f2bf(u.z), f2bf(u.w));
    }
}

// ================= shared staging/read/MFMA macros =================
#define READ_A(BA, MH)                                                          \
  _Pragma("unroll") for (int j = 0; j < 4; ++j)                                 \
    _Pragma("unroll") for (int kk = 0; kk < 2; ++kk)                            \
      a_[j][kk] = *(const bf16x8*)((BA) + (wr*8 + (MH)*4 + j)*2048 + kk*1024 + aoffb);

#define READ_A2(BA, MH)                                                         \
  _Pragma("unroll") for (int j = 0; j < 2; ++j)                                 \
    _Pragma("unroll") for (int kk = 0; kk < 2; ++kk)                            \
      a_[j][kk] = *(const bf16x8*)((BA) + (wr*4 + (MH)*2 + j)*2048 + kk*1024 + aoffb);

#define READ_B(BB, NH, BR)                                                      \
  _Pragma("unroll") for (int j2 = 0; j2 < 2; ++j2)                              \
    _Pragma("unroll") for (int kk = 0; kk < 2; ++kk)                            \
      BR[j2][kk] = *(const bf16x8*)((BB) + (wc*4 + (NH)*2 + j2)*2048 + kk*1024 + aoffb);

#define MFMA_Q(MH, NH, BR)                                                      \
  __builtin_amdgcn_s_setprio(1);                                                \
  _Pragma("unroll") for (int kk = 0; kk < 2; ++kk)                              \
    _Pragma("unroll") for (int j = 0; j < 4; ++j)                               \
      _Pragma("unroll") for (int j2 = 0; j2 < 2; ++j2)                          \
        asm volatile("v_mfma_f32_16x16x32_bf16 %0, %1, %2, %0"                  \
          : "+a"(acc[(MH)*4 + j][(NH)*2 + j2]) : "v"(a_[j][kk]), "v"(BR[j2][kk])); \
  __builtin_amdgcn_s_setprio(0);

#define MFMA_Q2(MH, NH, BR)                                                     \
  __builtin_amdgcn_s_setprio(1);                                                \
  _Pragma("unroll") for (int kk = 0; kk < 2; ++kk)                              \
    _Pragma("unroll") for (int j = 0; j < 2; ++j)                               \
      _Pragma("unroll") for (int j2 = 0; j2 < 2; ++j2)                          \
        asm volatile("v_mfma_f32_16x16x32_bf16 %0, %1, %2, %0"                  \
          : "+a"(acc[(MH)*2 + j][(NH)*2 + j2]) : "v"(a_[j][kk]), "v"(BR[j2][kk])); \
  __builtin_amdgcn_s_setprio(0);

#define BAR() __builtin_amdgcn_s_barrier()

// ================= 256x256 8-phase core (round-2 proven) =================
template<int KE, int LDE>
__device__ __forceinline__ void gemm8_core(const char* __restrict__ Ag, const char* __restrict__ Bg,
                                           char* lds, f32x4 (&acc)[8][4]) {
    constexpr int LD2 = LDE * 2;
    const int tid = threadIdx.x, l = tid & 63, w = tid >> 6;
    const int wr = w >> 2, wc = w & 3;
    const int term  = ((l >> 4) * 8) ^ (((l >> 3) & 1) << 4);
    const int aoffb = (l & 15) * 64 + term * 2;

    char* const A0 = lds;          char* const B0 = lds + 32768;
    char* const A1 = lds + 65536;  char* const B1 = lds + 98304;

    int offA[2][2], offB[2][2], dstA[2][2], dstB[2][2];
#pragma unroll
    for (int q = 0; q < 2; ++q) {
        const int s  = q * 8 + w;
        const int lr = l >> 2;
        const int h  = ((s >> 1) << 4) + lr;
        const int c  = ((s & 1) << 5) + (((l & 3) * 8) ^ ((l & 32) >> 1));
#pragma unroll
        for (int half = 0; half < 2; ++half) {
            const int rA = (h & 63) + ((h >> 6) << 7) + (half << 6);
            const int rB = (h & 31) + ((h >> 5) << 6) + (half << 5);
            offA[q][half] = rA * LD2 + c * 2;
            offB[q][half] = rB * LD2 + c * 2;
            dstA[q][half] = ((((s >> 1) & 3) + (half << 2) + ((s >> 3) << 3)) << 11) + ((s & 1) << 10);
            dstB[q][half] = ((((s >> 1) & 1) + (half << 1) + ((s >> 2) << 2)) << 11) + ((s & 1) << 10);
        }
    }
    auto SA = [&](char* dst, int half, int kt) {
        gload16(Ag + offA[0][half] + kt * 128, dst + dstA[0][half]);
        gload16(Ag + offA[1][half] + kt * 128, dst + dstA[1][half]);
    };
    auto SB = [&](char* dst, int half, int kt) {
        gload16(Bg + offB[0][half] + kt * 128, dst + dstB[0][half]);
        gload16(Bg + offB[1][half] + kt * 128, dst + dstB[1][half]);
    };

    SA(A0, 0, 0); SB(B0, 0, 0); SB(B0, 1, 0); SA(A0, 1, 0);
    SA(A1, 0, 1); SB(B1, 0, 1); SB(B1, 1, 1);
    asm volatile("s_waitcnt vmcnt(6)" ::: "memory");
    BAR();

    constexpr int NKT = KE / 64;
    bf16x8 a_[4][2], b0_[2][2], b1_[2][2];
#pragma unroll 1
    for (int k0 = 0; k0 < NKT; k0 += 2) {
        const int k1 = k0 + 1;
        READ_A(A0, 0) READ_B(B0, 0, b0_)
        SA(A1, 1, k1);
        BAR(); MFMA_Q(0, 0, b0_) BAR();
        READ_B(B0, 1, b1_)
        SA(A0, 0, k0 + 2);
        BAR(); MFMA_Q(0, 1, b1_) BAR();
        READ_A(A0, 1)
        SB(B0, 0, k0 + 2);
        BAR(); MFMA_Q(1, 1, b1_) BAR();
        SB(B0, 1, k0 + 2);
        asm volatile("s_waitcnt vmcnt(4)" ::: "memory");
        BAR(); MFMA_Q(1, 0, b0_) BAR();
        READ_A(A1, 0) READ_B(B1, 0, b0_)
        SA(A0, 1, k0 + 2);
        BAR(); MFMA_Q(0, 0, b0_) BAR();
        READ_B(B1, 1, b1_)
        SA(A1, 0, k1 + 2);
        BAR(); MFMA_Q(0, 1, b1_) BAR();
        READ_A(A1, 1)
        SB(B1, 0, k1 + 2);
        BAR(); MFMA_Q(1, 1, b1_) BAR();
        SB(B1, 1, k1 + 2);
        asm volatile("s_waitcnt vmcnt(4)" ::: "memory");
        BAR(); MFMA_Q(1, 0, b0_) BAR();
    }
}

// ================= 128x256 8-phase core (gemm2): A 16KB/buf, B 32KB/buf =================
// 8 waves 2Mx4N, per-wave 64x64, acc[4][4]. A staged with the proven B-geometry
// (1 gload/wave/half, halves by row bit5); quadrant = 2x2 frags.
template<int KE, int LDE>
__device__ __forceinline__ void gemm8m_core(const char* __restrict__ Ag, const char* __restrict__ Bg,
                                            char* lds, f32x4 (&acc)[4][4]) {
    constexpr int LD2 = LDE * 2;
    const int tid = threadIdx.x, l = tid & 63, w = tid >> 6;
    const int wr = w >> 2, wc = w & 3;
    const int term  = ((l >> 4) * 8) ^ (((l >> 3) & 1) << 4);
    const int aoffb = (l & 15) * 64 + term * 2;

    char* const A0 = lds;          char* const B0 = lds + 16384;
    char* const A1 = lds + 49152;  char* const B1 = lds + 65536;

    const int lr = l >> 2;
    // A: s = w (8 gloads/half total)
    int offA[2], dstA[2];
    {
        const int hA = ((w >> 1) << 4) + lr;                       // 0..63
        const int cA = ((w & 1) << 5) + (((l & 3) * 8) ^ ((l & 32) >> 1));
#pragma unroll
        for (int half = 0; half < 2; ++half) {
            const int rA = (hA & 31) + ((hA >> 5) << 6) + (half << 5);   // row bit5 = half
            offA[half] = rA * LD2 + cA * 2;
            dstA[half] = ((((w >> 1) & 1) + (half << 1) + ((w >> 2) << 2)) << 11) + ((w & 1) << 10);
        }
    }
    // B: s = q*8 + w (16 gloads/half total) -- identical to the 256-tile core
    int offB[2][2], dstB[2][2];
#pragma unroll
    for (int q = 0; q < 2; ++q) {
        const int s = q * 8 + w;
        const int h = ((s >> 1) << 4) + lr;
        const int c = ((s & 1) << 5) + (((l & 3) * 8) ^ ((l & 32) >> 1));
#pragma unroll
        for (int half = 0; half < 2; ++half) {
            const int rB = (h & 31) + ((h >> 5) << 6) + (half << 5);
            offB[q][half] = rB * LD2 + c * 2;
            dstB[q][half] = ((((s >> 1) & 1) + (half << 1) + ((s >> 2) << 2)) << 11) + ((s & 1) << 10);
        }
    }
    auto SA = [&](char* dst, int half, int kt) {
        gload16(Ag + offA[half] + kt * 128, dst + dstA[half]);
    };
    auto SB = [&](char* dst, int half, int kt) {
        gload16(Bg + offB[0][half] + kt * 128, dst + dstB[0][half]);
        gload16(Bg + offB[1][half] + kt * 128, dst + dstB[1][half]);
    };

    // prologue: kt0 (6 gloads) + kt1 partial (5) = 11 in flight; kt0 landed at vmcnt(5)
    SA(A0, 0, 0); SB(B0, 0, 0); SB(B0, 1, 0); SA(A0, 1, 0);
    SA(A1, 0, 1); SB(B1, 0, 1); SB(B1, 1, 1);
    asm volatile("s_waitcnt vmcnt(5)" ::: "memory");
    BAR();

    constexpr int NKT = KE / 64;
    bf16x8 a_[2][2], b0_[2][2], b1_[2][2];
#pragma unroll 1
    for (int k0 = 0; k0 < NKT; k0 += 2) {
        const int k1 = k0 + 1;
        READ_A2(A0, 0) READ_B(B0, 0, b0_)
        SA(A1, 1, k1);
        BAR(); MFMA_Q2(0, 0, b0_) BAR();
        READ_B(B0, 1, b1_)
        SA(A0, 0, k0 + 2);
        BAR(); MFMA_Q2(0, 1, b1_) BAR();
        READ_A2(A0, 1)
        SB(B0, 0, k0 + 2);
        BAR(); MFMA_Q2(1, 1, b1_) BAR();
        SB(B0, 1, k0 + 2);
        asm volatile("s_waitcnt vmcnt(5)" ::: "memory");   // kt1 landed; 5 = ph2..ph4 stages
        BAR(); MFMA_Q2(1, 0, b0_) BAR();
        READ_A2(A1, 0) READ_B(B1, 0, b0_)
        SA(A0, 1, k0 + 2);
        BAR(); MFMA_Q2(0, 0, b0_) BAR();
        READ_B(B1, 1, b1_)
        SA(A1, 0, k1 + 2);
        BAR(); MFMA_Q2(0, 1, b1_) BAR();
        READ_A2(A1, 1)
        SB(B1, 0, k1 + 2);
        BAR(); MFMA_Q2(1, 1, b1_) BAR();
        SB(B1, 1, k1 + 2);
        asm volatile("s_waitcnt vmcnt(5)" ::: "memory");   // kt2 landed; 5 = ph6..ph8 stages
        BAR(); MFMA_Q2(1, 0, b0_) BAR();
    }
}

// ---------------- GEMM1: inter = gelu(A @ w1[e]^T + b1[e]) ----------------
// 2-D grid (16 panels x 40 tiles), x fastest — round-2 measured-good ordering.
__global__ void __launch_bounds__(512, 2)
gemm1_k(const unsigned short* __restrict__ ab, const unsigned short* __restrict__ w1b,
        const float* __restrict__ b1, unsigned short* __restrict__ inter,
        const int* __restrict__ tile_e, const int* __restrict__ tile_r0,
        const int* __restrict__ ntiles, const int* __restrict__ offs) {
    if ((int)blockIdx.y >= *ntiles) return;
    __shared__ char lds[131072];
    const int e = tile_e[blockIdx.y], row0 = tile_r0[blockIdx.y];
    const int f0 = blockIdx.x * 256;
    f32x4 acc[8][4];
#pragma unroll
    for (int m = 0; m < 8; ++m)
#pragma unroll
        for (int n = 0; n < 4; ++n)
#pragma unroll
            for (int j = 0; j < 4; ++j) acc[m][n][j] = 0.f;

    gemm8_core<H, H>((const char*)(ab + (size_t)row0 * H),
                     (const char*)(w1b + ((size_t)e * FF + f0) * H), lds, acc);

    // drain in-flight overrun stages before reusing LDS, then repack C via LDS
    asm volatile("s_waitcnt vmcnt(0)" ::: "memory");
    __syncthreads();
    const int tid = threadIdx.x, l = tid & 63, w = tid >> 6, wr = w >> 2, wc = w & 3;
    const int q = (l >> 4) & 3, lc = l & 15;
    unsigned short* cl = (unsigned short*)lds;
    float bias[4];
#pragma unroll
    for (int n = 0; n < 4; ++n) bias[n] = b1[e * FF + f0 + wc * 64 + n * 16 + lc];
    const int rowb = wr * 128 + q * 4;
#pragma unroll
    for (int n = 0; n < 4; ++n) {
        const int coln = (wc * 64 + n * 16 + lc) ^ (q << 4);
#pragma unroll
        for (int m = 0; m < 8; ++m)
#pragma unroll
            for (int j = 0; j < 4; ++j) {
                float v = acc[m][n][j] + bias[n];
                float ex = __expf(1.5957691216057308f * v * (1.0f + 0.044715f * v * v));
                float u  = v - v / (ex + 1.0f);
                cl[(rowb + m * 16 + j) * 256 + coln] = f2bf(u);
            }
    }
    __syncthreads();
    const int rend = offs[e + 1];
    const int rsub = tid >> 5, cblk = (tid & 31) * 8;
    const int rxor = ((rsub >> 2) & 3) << 4;
#pragma unroll
    for (int it = 0; it < 16; ++it) {
        const int r = it * 16 + rsub;
        if (row0 + r < rend) {
            ushort8 val = *(const ushort8*)&cl[r * 256 + (cblk ^ rxor)];
            *(ushort8*)&inter[(size_t)(row0 + r) * FF + f0 + cblk] = val;
        }
    }
}

// ---------------- GEMM2: out = (inter @ w2[e]^T)*p scattered; outb fused ----------------
// 128x256 tiles, grid 288 = 72 tiles x 4 panels; tile-outer/panel-inner XCD chunks
// so the 4 co-resident panel-blocks of a tile share its A fetch in L2.
__global__ void __launch_bounds__(512, 2)
gemm2_k(const unsigned short* __restrict__ inter, const unsigned short* __restrict__ w2b,
        const float* __restrict__ b2, float* __restrict__ out, float* __restrict__ outb,
        const int* __restrict__ t128_e, const int* __restrict__ t128_r0, const int* __restrict__ nt128,
        const int* __restrict__ counts, const int* __restrict__ offs,
        const int* __restrict__ perm, const float* __restrict__ maxp) {
    const int bid = blockIdx.x;
    const int wkid = (bid & 7) * 36 + (bid >> 3);   // bijective, 288 % 8 == 0
    const int yb = wkid >> 2, xb = wkid & 3;
    if (yb >= *nt128) return;
    __shared__ char lds[98304];
    const int e = t128_e[yb], row0 = t128_r0[yb];
    const int h0 = xb * 256;
    f32x4 acc[4][4];
#pragma unroll
    for (int m = 0; m < 4; ++m)
#pragma unroll
        for (int n = 0; n < 4; ++n)
#pragma unroll
            for (int j = 0; j < 4; ++j) acc[m][n][j] = 0.f;

    gemm8m_core<FF, FF>((const char*)(inter + (size_t)row0 * FF),
                        (const char*)(w2b + ((size_t)e * H + h0) * FF), lds, acc);

    const int l = threadIdx.x & 63, w = threadIdx.x >> 6, wr = w >> 2, wc = w & 3;
    const int cnt = counts[e * 32], offe = offs[e];
#pragma unroll
    for (int m = 0; m < 4; ++m) {
#pragma unroll
        for (int j = 0; j < 4; ++j) {
            const int grow = row0 + wr * 64 + m * 16 + ((l >> 4) << 2) + j;
            if (grow - offe < cnt) {
                const int t = perm[grow];
                const float p = maxp[t];
#pragma unroll
                for (int n = 0; n < 4; ++n) {
                    const int col = h0 + wc * 64 + n * 16 + (l & 15);
                    out [(size_t)t * H + col] = acc[m][n][j] * p;
                    outb[(size_t)t * H + col] = b2[e * H + col] * p;
                }
            }
        }
    }
}

// ---------------- host launch ----------------
extern "C" void kernel_launch(void* const* d_in, const int* in_sizes, int n_in,
                              void* d_out, int out_size, void* d_ws, size_t ws_size,
                              hipStream_t stream) {
    const float* x  = (const float*)d_in[0];
    const float* rw = (const float*)d_in[1];
    const float* rb = (const float*)d_in[2];
    const float* w1 = (const float*)d_in[3];
    const float* b1 = (const float*)d_in[4];
    const float* w2 = (const float*)d_in[5];
    const float* b2 = (const float*)d_in[6];
    float* out  = (float*)d_out;
    float* outb = out + (size_t)NTOK * H;

    char* ws = (char*)d_ws;
    unsigned short* W1B   = (unsigned short*)(ws);                 // 67108864
    unsigned short* W2B   = (unsigned short*)(ws + 67108864);      // 67108864
    unsigned short* AB    = (unsigned short*)(ws + 134217728);     // 18874368 (9216 x 1024)
    unsigned short* INTER = (unsigned short*)(ws + 153092096);     // 75497472 (9216 x 4096)
    float* MAXP    = (float*)(ws + 228589568);
    int*   MAXI    = (int*)  (ws + 228622336);
    int*   PERM    = (int*)  (ws + 228655104);
    int*   COUNTS  = (int*)  (ws + 228691968);
    int*   CURSOR  = (int*)  (ws + 228692992);
    int*   OFFS    = (int*)  (ws + 228694016);
    int*   TILE_E  = (int*)  (ws + 228694080);
    int*   TILE_R0 = (int*)  (ws + 228694336);
    int*   NTILES  = (int*)  (ws + 228694592);
    int*   T128_E  = (int*)  (ws + 228694656);
    int*   T128_R0 = (int*)  (ws + 228695168);
    int*   NT128   = (int*)  (ws + 228695680);

    (void)hipMemsetAsync(COUNTS, 0, 2048, stream);   // counts + cursors

    router_k<<<NTOK / 4, 256, 0, stream>>>(x, rw, rb, MAXP, MAXI, COUNTS);
    scan_k<<<1, 1, 0, stream>>>(COUNTS, OFFS, TILE_E, TILE_R0, NTILES, T128_E, T128_R0, NT128);
    gather_k<<<NTOK / 4, 256, 0, stream>>>(x, MAXI, OFFS, CURSOR, PERM, AB);
    cvt_k<<<4096, 256, 0, stream>>>((const float4*)w1, (const float4*)w2,
                                    (ushort4*)W1B, (ushort4*)W2B, NEXP * FF * H / 4);
    gemm1_k<<<dim3(FF / 256, MAXTILES), 512, 0, stream>>>(AB, W1B, b1, INTER,
                                                          TILE_E, TILE_R0, NTILES, OFFS);
    gemm2_k<<<4 * MAXT128, 512, 0, stream>>>(INTER, W2B, b2, out, outb,
                                             T128_E, T128_R0, NT128,
                                             COUNTS, OFFS, PERM, MAXP);
}

// Round 5
// 350.784 us; speedup vs baseline: 2.0613x; 1.4067x over previous
//
#include <hip/hip_runtime.h>
#include <math.h>

// ---------------- types ----------------
typedef float  f32x4  __attribute__((ext_vector_type(4)));
typedef short  bf16x8 __attribute__((ext_vector_type(8)));

#define NTOK 8192
#define H    1024
#define FF   4096
#define NEXP 8
#define MAXT128 72   // 128-row tiles: sum ceil(c_e/128) <= 8192/128 + 8

// fp32 -> bf16 RNE
__device__ __forceinline__ unsigned short f2bf(float f) {
    unsigned int u = __float_as_uint(f);
    u += 0x7fffu + ((u >> 16) & 1u);
    return (unsigned short)(u >> 16);
}

// async global->LDS, 16B/lane; LDS dest = wave-uniform base + lane*16
__device__ __forceinline__ void gload16(const void* g, void* l) {
    __builtin_amdgcn_global_load_lds((const __attribute__((address_space(1))) void*)g,
                                     (__attribute__((address_space(3))) void*)l, 16, 0, 0);
}

// ---------------- router: 1 wave per token ----------------
__global__ void __launch_bounds__(256)
router_k(const float* __restrict__ x, const float* __restrict__ rw, const float* __restrict__ rb,
         float* __restrict__ maxp, int* __restrict__ maxi, int* __restrict__ counts) {
    const int lane = threadIdx.x & 63;
    const int t = blockIdx.x * 4 + (threadIdx.x >> 6);
    const float4* xr = (const float4*)(x + (size_t)t * H);
    float acc[NEXP];
#pragma unroll
    for (int e = 0; e < NEXP; ++e) acc[e] = 0.f;
#pragma unroll
    for (int c = 0; c < 4; ++c) {
        float4 xv = xr[lane + 64 * c];
#pragma unroll
        for (int e = 0; e < NEXP; ++e) {
            float4 wv = ((const float4*)(rw + e * H))[lane + 64 * c];
            acc[e] += xv.x * wv.x + xv.y * wv.y + xv.z * wv.z + xv.w * wv.w;
        }
    }
#pragma unroll
    for (int e = 0; e < NEXP; ++e) {
#pragma unroll
        for (int off = 32; off > 0; off >>= 1) acc[e] += __shfl_xor(acc[e], off);
    }
    if (lane == 0) {
        float best = -1e30f; int bi = 0;
#pragma unroll
        for (int e = 0; e < NEXP; ++e) {
            float v = acc[e] + rb[e];
            acc[e] = v;
            if (v > best) { best = v; bi = e; }   // first-max tie-break like jnp.argmax
        }
        float s = 0.f;
#pragma unroll
        for (int e = 0; e < NEXP; ++e) s += __expf(acc[e] - best);
        maxp[t] = 1.0f / s;                       // max of softmax
        maxi[t] = bi;
        atomicAdd(&counts[bi * 32], 1);           // 128B-padded: 8 independent L2 lines
    }
}

// ---------------- scan: bucket offsets (128-aligned) + 128-row tile table ----------------
__global__ void scan_k(const int* __restrict__ counts, int* __restrict__ offs,
                       int* __restrict__ tile_e, int* __restrict__ tile_r0, int* __restrict__ ntiles) {
    int off = 0, ti = 0;
    for (int e = 0; e < NEXP; ++e) {
        offs[e] = off;
        int nt = (counts[e * 32] + 127) >> 7;
        for (int j = 0; j < nt; ++j) { tile_e[ti] = e; tile_r0[ti] = off + (j << 7); ++ti; }
        off += nt << 7;
    }
    offs[NEXP] = off;
    *ntiles = ti;
}

// ---------------- gather tokens into bucketed bf16 A ----------------
__global__ void __launch_bounds__(256)
gather_k(const float* __restrict__ x, const int* __restrict__ maxi, const int* __restrict__ offs,
         int* __restrict__ cursor, int* __restrict__ perm, unsigned short* __restrict__ ab) {
    const int lane = threadIdx.x & 63;
    const int t = blockIdx.x * 4 + (threadIdx.x >> 6);
    int pos = 0;
    if (lane == 0) {
        int e = maxi[t];
        pos = offs[e] + atomicAdd(&cursor[e * 32], 1);   // padded cursors
        perm[pos] = t;
    }
    pos = __shfl(pos, 0);
    const float4* xr = (const float4*)(x + (size_t)t * H);
    ushort4* ar = (ushort4*)(ab + (size_t)pos * H);
#pragma unroll
    for (int c = 0; c < 4; ++c) {
        float4 v = xr[lane + 64 * c];
        ar[lane + 64 * c] = make_ushort4(f2bf(v.x), f2bf(v.y), f2bf(v.z), f2bf(v.w));
    }
}

// ---------------- fp32 -> bf16 convert, w1+w2 in one pass ----------------
__global__ void __launch_bounds__(256)
cvt_k(const float4* __restrict__ w1, const float4* __restrict__ w2,
      ushort4* __restrict__ d1, ushort4* __restrict__ d2, int n4) {
    const int stride = gridDim.x * blockDim.x;
    for (int i = blockIdx.x * blockDim.x + threadIdx.x; i < n4; i += stride) {
        float4 v = w1[i]; d1[i] = make_ushort4(f2bf(v.x), f2bf(v.y), f2bf(v.z), f2bf(v.w));
        float4 u = w2[i]; d2[i] = make_ushort4(f2bf(u.x), f2bf(u.y), f2bf(u.z), f2bf(u.w));
    }
}

// ---------------- GEMM core (round-1 measured-best, verbatim) ----------------
// C[128x128] += A[128xK] * B[128xK]^T (both bf16 row-major, stride KB bytes).
// m97 structure: global_load_lds(16B) staging, 2 barriers / 64-elem K-step,
// 16x16x32 MFMA. LDS XOR-swizzle: linear LDS dest, inverse-swizzled GLOBAL
// source, swizzled ds_read (rule #21 pair).
template<int KB>   // row stride in bytes (= 2*K)
__device__ __forceinline__ void gemm_core(const char* Ag, const char* Bg,
                                          unsigned short* As, unsigned short* Bs,
                                          f32x4 (&acc)[4][4]) {
    const int tid  = threadIdx.x;
    const int lane = tid & 63;
    const int wv   = tid >> 6;          // 4 waves, 2x2 over tile; each wave 64x64
    const int wr   = wv >> 1, wc = wv & 1;

    int goff[4];
#pragma unroll
    for (int c = 0; c < 4; ++c) {
        int op = c * 4096 + wv * 1024 + lane * 16;          // physical LDS byte this lane fills
        int ol = op ^ (((op >> 7) & 7) << 4);               // logical offset (swz is an involution)
        goff[c] = (ol >> 7) * KB + (ol & 127);              // row*stride + col bytes
    }
    const int rA  = (wr * 64 + (lane & 15)) * 128;
    const int rB  = (wc * 64 + (lane & 15)) * 128;
    const int xr  = (lane & 7) << 4;                        // (row&7)<<4 swizzle on read
    const int cb0 = (lane >> 4) << 4;

#pragma unroll 1
    for (int kt = 0; kt < KB / 128; ++kt) {
        const int kb = kt * 128;
#pragma unroll
        for (int c = 0; c < 4; ++c)
            gload16(Ag + goff[c] + kb, (char*)As + c * 4096 + wv * 1024);
#pragma unroll
        for (int c = 0; c < 4; ++c)
            gload16(Bg + goff[c] + kb, (char*)Bs + c * 4096 + wv * 1024);
        __syncthreads();                                    // drains vmcnt(0) for the LDS DMA
#pragma unroll
        for (int kk = 0; kk < 2; ++kk) {
            bf16x8 a[4], b[4];
            const int cb = kk * 64 + cb0;
#pragma unroll
            for (int m = 0; m < 4; ++m)
                a[m] = *(const bf16x8*)((const char*)As + ((rA + m * 2048 + cb) ^ xr));
#pragma unroll
            for (int n = 0; n < 4; ++n)
                b[n] = *(const bf16x8*)((const char*)Bs + ((rB + n * 2048 + cb) ^ xr));
#pragma unroll
            for (int m = 0; m < 4; ++m)
#pragma unroll
                for (int n = 0; n < 4; ++n)
                    asm volatile("v_mfma_f32_16x16x32_bf16 %0, %1, %2, %0"
                                 : "+v"(acc[m][n]) : "v"(a[m]), "v"(b[n]));
        }
        __syncthreads();
    }
}

// ---------------- GEMM1: inter = gelu(A @ w1[e]^T + b1[e]) ----------------
__global__ void __launch_bounds__(256)
gemm1_k(const unsigned short* __restrict__ ab, const unsigned short* __restrict__ w1b,
        const float* __restrict__ b1, unsigned short* __restrict__ inter,
        const int* __restrict__ tile_e, const int* __restrict__ tile_r0,
        const int* __restrict__ ntiles) {
    if ((int)blockIdx.y >= *ntiles) return;
    __shared__ alignas(16) unsigned short As[128 * 64];
    __shared__ alignas(16) unsigned short Bs[128 * 64];
    const int e    = tile_e[blockIdx.y];
    const int row0 = tile_r0[blockIdx.y];
    const int f0   = blockIdx.x * 128;
    f32x4 acc[4][4];
#pragma unroll
    for (int m = 0; m < 4; ++m)
#pragma unroll
        for (int n = 0; n < 4; ++n)
#pragma unroll
            for (int j = 0; j < 4; ++j) acc[m][n][j] = 0.f;

    gemm_core<2 * H>((const char*)(ab + (size_t)row0 * H),
                     (const char*)(w1b + ((size_t)e * FF + f0) * H), As, Bs, acc);

    const int lane = threadIdx.x & 63;
    const int wv = threadIdx.x >> 6, wr = wv >> 1, wc = wv & 1;
    const int lr = (lane >> 4) << 2, lc = lane & 15;        // C/D: col=lane&15, row=(lane>>4)*4+reg
#pragma unroll
    for (int n = 0; n < 4; ++n) {
        const int gcol = f0 + wc * 64 + n * 16 + lc;
        const float bias = b1[e * FF + gcol];
#pragma unroll
        for (int m = 0; m < 4; ++m) {
            const int gr0 = row0 + wr * 64 + m * 16 + lr;
#pragma unroll
            for (int r = 0; r < 4; ++r) {
                float v = acc[m][n][r] + bias;
                // 0.5v(1+tanh(z)) = v - v/(e^{2z}+1), z = 0.79788456*v*(1+0.044715 v^2)
                float ex = __expf(1.5957691216057308f * v * (1.0f + 0.044715f * v * v));
                float u  = v - v / (ex + 1.0f);
                inter[(size_t)(gr0 + r) * FF + gcol] = f2bf(u);
            }
        }
    }
}

// ---------------- GEMM2: out[token] = (inter @ w2[e]^T) * max_prob, scattered ----------------
__global__ void __launch_bounds__(256)
gemm2_k(const unsigned short* __restrict__ inter, const unsigned short* __restrict__ w2b,
        float* __restrict__ out,
        const int* __restrict__ tile_e, const int* __restrict__ tile_r0, const int* __restrict__ ntiles,
        const int* __restrict__ counts, const int* __restrict__ offs,
        const int* __restrict__ perm, const float* __restrict__ maxp) {
    if ((int)blockIdx.y >= *ntiles) return;
    __shared__ alignas(16) unsigned short As[128 * 64];
    __shared__ alignas(16) unsigned short Bs[128 * 64];
    const int e    = tile_e[blockIdx.y];
    const int row0 = tile_r0[blockIdx.y];
    const int h0   = blockIdx.x * 128;
    f32x4 acc[4][4];
#pragma unroll
    for (int m = 0; m < 4; ++m)
#pragma unroll
        for (int n = 0; n < 4; ++n)
#pragma unroll
            for (int j = 0; j < 4; ++j) acc[m][n][j] = 0.f;

    gemm_core<2 * FF>((const char*)(inter + (size_t)row0 * FF),
                      (const char*)(w2b + ((size_t)e * H + h0) * FF), As, Bs, acc);

    const int lane = threadIdx.x & 63;
    const int wv = threadIdx.x >> 6, wr = wv >> 1, wc = wv & 1;
    const int lr = (lane >> 4) << 2, lc = lane & 15;
    const int cnt = counts[e * 32], offe = offs[e];
#pragma unroll
    for (int m = 0; m < 4; ++m) {
#pragma unroll
        for (int r = 0; r < 4; ++r) {
            const int grow = row0 + wr * 64 + m * 16 + lr + r;
            if (grow - offe < cnt) {                         // skip padding rows
                const int t = perm[grow];
                const float p = maxp[t];
#pragma unroll
                for (int n = 0; n < 4; ++n)
                    out[(size_t)t * H + h0 + wc * 64 + n * 16 + lc] = acc[m][n][r] * p;
            }
        }
    }
}

// ---------------- out_bias = b2[e] * max_prob (coalesced, separate) ----------------
__global__ void __launch_bounds__(256)
bias_k(const float* __restrict__ b2, const int* __restrict__ maxi, const float* __restrict__ maxp,
       float* __restrict__ outb) {
    const int t = blockIdx.x;
    const int c = threadIdx.x;
    const int e = maxi[t];
    const float p = maxp[t];
    float4 v = ((const float4*)(b2 + e * H))[c];
    float4 r; r.x = v.x * p; r.y = v.y * p; r.z = v.z * p; r.w = v.w * p;
    ((float4*)(outb + (size_t)t * H))[c] = r;
}

// ---------------- host launch ----------------
extern "C" void kernel_launch(void* const* d_in, const int* in_sizes, int n_in,
                              void* d_out, int out_size, void* d_ws, size_t ws_size,
                              hipStream_t stream) {
    const float* x  = (const float*)d_in[0];
    const float* rw = (const float*)d_in[1];
    const float* rb = (const float*)d_in[2];
    const float* w1 = (const float*)d_in[3];
    const float* b1 = (const float*)d_in[4];
    const float* w2 = (const float*)d_in[5];
    const float* b2 = (const float*)d_in[6];
    float* out  = (float*)d_out;                    // [8192][1024]
    float* outb = out + (size_t)NTOK * H;           // second tuple element

    // workspace layout (~219 MB)
    char* ws = (char*)d_ws;
    unsigned short* W1B   = (unsigned short*)(ws);                 //  67108864 B
    unsigned short* W2B   = (unsigned short*)(ws + 67108864);      //  67108864 B
    unsigned short* AB    = (unsigned short*)(ws + 134217728);     //  18874368 B (9216 x 1024 bf16)
    unsigned short* INTER = (unsigned short*)(ws + 153092096);     //  75497472 B (9216 x 4096 bf16)
    float* MAXP    = (float*)(ws + 228589568);                     //  32768 B
    int*   MAXI    = (int*)  (ws + 228622336);                     //  32768 B
    int*   PERM    = (int*)  (ws + 228655104);                     //  36864 B
    int*   COUNTS  = (int*)  (ws + 228691968);                     //  1024 B (8 x 128B)
    int*   CURSOR  = (int*)  (ws + 228692992);                     //  1024 B
    int*   OFFS    = (int*)  (ws + 228694016);                     //  64 B
    int*   TILE_E  = (int*)  (ws + 228694080);                     //  512 B
    int*   TILE_R0 = (int*)  (ws + 228694592);                     //  512 B
    int*   NTILES  = (int*)  (ws + 228695104);

    (void)hipMemsetAsync(COUNTS, 0, 2048, stream);  // counts + cursors

    router_k<<<NTOK / 4, 256, 0, stream>>>(x, rw, rb, MAXP, MAXI, COUNTS);
    scan_k<<<1, 1, 0, stream>>>(COUNTS, OFFS, TILE_E, TILE_R0, NTILES);
    gather_k<<<NTOK / 4, 256, 0, stream>>>(x, MAXI, OFFS, CURSOR, PERM, AB);
    cvt_k<<<4096, 256, 0, stream>>>((const float4*)w1, (const float4*)w2,
                                    (ushort4*)W1B, (ushort4*)W2B, NEXP * FF * H / 4);
    gemm1_k<<<dim3(FF / 128, MAXT128), 256, 0, stream>>>(AB, W1B, b1, INTER,
                                                         TILE_E, TILE_R0, NTILES);
    gemm2_k<<<dim3(H / 128, MAXT128), 256, 0, stream>>>(INTER, W2B, out, TILE_E, TILE_R0, NTILES,
                                                        COUNTS, OFFS, PERM, MAXP);
    bias_k<<<NTOK, 256, 0, stream>>>(b2, MAXI, MAXP, outb);
}